// Round 8
// baseline (381.958 us; speedup 1.0000x reference)
//
#include <hip/hip_runtime.h>
#include <math.h>

// Problem constants
#define BB   512   // batch
#define TT   256   // timesteps
#define CNNC 512   // channels
#define VV   37    // vocab
#define HH   8     // hidden
#define G4   32    // 4*H
#define CH   32    // chunk length (timesteps)
#define NCK  8     // TT/CH

#define L2E 1.4426950408889634f

// native 4-float vector for nontemporal builtins (HIP float4 is a class type)
typedef float f4_t __attribute__((ext_vector_type(4)));

// DPP cross-lane mov: pure VALU latency. quad_perm 0xB1=xor1, 0x4E=xor2,
// 0x1B=xor3; 0x141=row_half_mirror (xor7); 0x140=row_mirror (xor15).
template <int CTRL>
__device__ __forceinline__ float dpp_f(float x) {
    int r = __builtin_amdgcn_update_dpp(0, __float_as_int(x), CTRL, 0xF, 0xF, true);
    return __int_as_float(r);
}
__device__ __forceinline__ float rcp_f(float x) { return __builtin_amdgcn_rcpf(x); }
__device__ __forceinline__ float exp2_f(float x) { return __builtin_amdgcn_exp2f(x); }

// ---------------------------------------------------------------------------
// Kernel 1: avg-pool(features) @ W_in.T partial -> featp[quarter][B][V]
// (unchanged from R7: 25 KB LDS, grid (512,4), NT loads)
// ---------------------------------------------------------------------------
__global__ __launch_bounds__(256) void k_feat(const float* __restrict__ features,
                                              const float* __restrict__ W_in,
                                              const float* __restrict__ b_in,
                                              float* __restrict__ featp) {
    __shared__ __align__(16) float raw[128 * 49];
    __shared__ float pooled[128];
    const int b = blockIdx.x, qt = blockIdx.y, tid = threadIdx.x;
    const f4_t* src =
        (const f4_t*)(features + (size_t)b * CNNC * 49 + qt * (128 * 49));
    f4_t* dst = (f4_t*)raw;
    for (int i = tid; i < 128 * 49 / 4; i += 256)
        dst[i] = __builtin_nontemporal_load(&src[i]);
    __syncthreads();
    if (tid < 128) {
        const float* p = raw + tid * 49;
        float s = 0.f;
        #pragma unroll
        for (int i = 0; i < 49; ++i) s += p[i];
        pooled[tid] = s;
    }
    __syncthreads();
    const int v = tid >> 2, pp = tid & 3;
    if (v < VV) {
        const float* w = W_in + v * CNNC + qt * 128 + pp * 32;
        const float* q = pooled + pp * 32;
        float s = 0.f;
        #pragma unroll
        for (int i = 0; i < 32; ++i) s += q[i] * w[i];
        s += __shfl_xor(s, 1);
        s += __shfl_xor(s, 2);
        if (pp == 0)
            featp[(qt * BB + b) * VV + v] =
                s * (1.f / 49.f) + (qt == 0 ? b_in[v] : 0.f);
    }
}

// ---------------------------------------------------------------------------
// Kernel 2: FUSED xproj + LSTM scan + softmax head. 128 blocks x 256 threads
// (4 waves), 1 block/CU. Per iteration ck (0..8), one __syncthreads:
//   wave 0: scan chunk ck (R6 DPP scan) from xbuf[ck%2], h -> hlds[ck%2]
//   waves 1,2: produce chunk ck+1 gates into xbuf[(ck+1)%2]
//              (x from cap LDS b128; W_ih via wave-uniform scalar loads)
//   wave 3: softmax chunk ck-1 from hlds -> coalesced NT writes;
//           stage captions chunk ck+2 -> cap[(ck+2)%2]
// Kills the xproj/hbuf global round-trips and 2 launch boundaries.
// ---------------------------------------------------------------------------
#define XSTR 133            // xbuf per-t stride (odd*4+1 -> <=2-way banks)
#define XBUF 4400           // floats per xbuf buffer (32*133=4256 + margin)
#define CSEQ 1280           // cap floats per seq (32 rows padded to 40)
#define OSTR 1188           // ostage per-seq stride (mult of 4, bank-spread)

__device__ __forceinline__ void stage_chunk(float* __restrict__ cap,
                                            const float* __restrict__ captions,
                                            int b0, int buf, int cc,
                                            int lane, int nthreads) {
    float* cb = cap + buf * (4 * CSEQ);
    if (cc == 0) {   // rows 1..31 <- captions rows 0..30 (t=0 uses feat)
        for (int i = lane; i < 4 * 1147; i += nthreads) {
            const int s = i / 1147, o = i - s * 1147;
            const int row = o / 37, v = o - row * 37;
            cb[s * CSEQ + (row + 1) * 40 + v] = __builtin_nontemporal_load(
                &captions[(size_t)(b0 + s) * TT * VV + o]);
        }
    } else {         // rows 0..31 <- captions rows cc*32-1 .. cc*32+30
        const int src0 = (cc * 32 - 1) * 37;
        for (int i = lane; i < 4 * 1184; i += nthreads) {
            const int s = i / 1184, o = i - s * 1184;
            const int row = o / 37, v = o - row * 37;
            cb[s * CSEQ + row * 40 + v] = __builtin_nontemporal_load(
                &captions[(size_t)(b0 + s) * TT * VV + src0 + o]);
        }
    }
}

__device__ __forceinline__ void produce_chunk(float* __restrict__ xb,
                                              const float* __restrict__ cap_s,
                                              const float* __restrict__ W_ih,
                                              const float* __restrict__ b_ih,
                                              const float* __restrict__ b_hh,
                                              const float* __restrict__ featp,
                                              int b0, int cc, int lt, int s) {
    float xr[40];
    if (cc == 0 && lt == 0) {
        const int b = b0 + s;
        #pragma unroll
        for (int v = 0; v < VV; ++v)
            xr[v] = featp[b * VV + v] + featp[(BB + b) * VV + v] +
                    featp[(2 * BB + b) * VV + v] + featp[(3 * BB + b) * VV + v];
    } else {
        const f4_t* xp4 = (const f4_t*)(cap_s + s * CSEQ + lt * 40);
        #pragma unroll
        for (int v4 = 0; v4 < 10; ++v4) {
            const f4_t x4 = xp4[v4];
            xr[v4 * 4 + 0] = x4.x; xr[v4 * 4 + 1] = x4.y;
            xr[v4 * 4 + 2] = x4.z; xr[v4 * 4 + 3] = x4.w;
        }
    }
    float* od = xb + lt * XSTR + s;
    #pragma unroll
    for (int g = 0; g < G4; ++g) {
        float acc = b_ih[g] + b_hh[g];            // wave-uniform scalar loads
        #pragma unroll
        for (int v = 0; v < VV; ++v) acc = fmaf(W_ih[g * VV + v], xr[v], acc);
        const float sc = (g >= 16 && g < 24) ? (-2.f * L2E) : (-L2E);
        od[g * 4] = acc * sc;
    }
}

__device__ __forceinline__ void consume_chunk(const float* __restrict__ hl,
                                              float* __restrict__ ostage,
                                              const float* __restrict__ W_out,
                                              const float* __restrict__ b_out,
                                              float* __restrict__ out,
                                              int b0, int cc, int wl) {
    #pragma unroll
    for (int k = 0; k < 2; ++k) {
        const int rid = wl + 64 * k;
        const int s = rid >> 5, lt = rid & 31;
        const f4_t* hp = (const f4_t*)(hl + (lt * 4 + s) * 8);
        const f4_t h0 = hp[0], h1 = hp[1];
        const float hr[8] = {h0.x, h0.y, h0.z, h0.w, h1.x, h1.y, h1.z, h1.w};
        float z[VV], m = -1e30f;
        #pragma unroll
        for (int v = 0; v < VV; ++v) {
            float sv = b_out[v];                  // uniform scalar loads
            #pragma unroll
            for (int kk = 0; kk < 8; ++kk)
                sv = fmaf(hr[kk], W_out[v * 8 + kk], sv);
            z[v] = sv; m = fmaxf(m, sv);
        }
        float sum = 0.f;
        #pragma unroll
        for (int v = 0; v < VV; ++v) { z[v] = exp2_f((z[v] - m) * L2E); sum += z[v]; }
        const float rs = rcp_f(sum);
        #pragma unroll
        for (int v = 0; v < VV; ++v) ostage[s * OSTR + lt * 37 + v] = z[v] * rs;
    }
    asm volatile("s_waitcnt lgkmcnt(0)" ::: "memory");
    for (int i = wl; i < 4 * 296; i += 64) {
        const int s = i / 296, o = i - s * 296;
        const f4_t val = *(const f4_t*)&ostage[s * OSTR + o * 4];
        f4_t* dst = (f4_t*)(out + ((size_t)(b0 + s) * TT + cc * 32) * VV) + o;
        __builtin_nontemporal_store(val, dst);
    }
}

__global__ __launch_bounds__(256) void k_fused(const float* __restrict__ captions,
                                               const float* __restrict__ W_ih,
                                               const float* __restrict__ b_ih,
                                               const float* __restrict__ b_hh,
                                               const float* __restrict__ W_hh,
                                               const float* __restrict__ W_out,
                                               const float* __restrict__ b_out,
                                               const float* __restrict__ featp,
                                               float* __restrict__ out) {
    __shared__ __align__(16) float cap[2 * 4 * CSEQ];   // 40960 B
    __shared__ __align__(16) float xbuf[2 * XBUF];      // 35200 B
    __shared__ __align__(16) float hlds[2 * 1024];      // 8192 B
    __shared__ __align__(16) float ostage[4 * OSTR];    // 19008 B

    const int tid = threadIdx.x;
    const int wid = tid >> 6, wl = tid & 63;
    const int bg = blockIdx.x, b0 = bg * 4;

    // scanner per-lane setup (wave 0 only)
    float wA[HH] = {0}, wB[HH] = {0};
    int s4 = 0, j = 0, r = 0, roff = 0;
    if (wid == 0) {
        s4 = wl >> 4;
        const int q = wl & 15;
        j = q >> 1; r = q & 1;
        const int rowA = r * 8 + j, rowB = 16 + r * 8 + j;
        const float scA = -L2E, scB = r ? -L2E : (-2.f * L2E);
        #pragma unroll
        for (int m = 0; m < HH; ++m) {
            wA[m] = scA * W_hh[rowA * HH + (j ^ m)];
            wB[m] = scB * W_hh[rowB * HH + (j ^ m)];
        }
        roff = rowA * 4 + s4;
    }

    // prologue: stage cap chunks 0,1 (all threads), then xproj chunk 0
    stage_chunk(cap, captions, b0, 0, 0, tid, 256);
    stage_chunk(cap, captions, b0, 1, 1, tid, 256);
    __syncthreads();
    if (wid == 1 || wid == 2) {
        const int p = (wid - 1) * 64 + wl;
        produce_chunk(&xbuf[0], &cap[0], W_ih, b_ih, b_hh, featp,
                      b0, 0, p & 31, p >> 5);
    }
    __syncthreads();

    float h = 0.f, c = 0.f;
    for (int ck = 0; ck <= NCK; ++ck) {
        if (wid == 0) {
            if (ck < NCK) {
                const float* base = &xbuf[(ck & 1) * XBUF] + roff;
                float* hl = &hlds[(ck & 1) * 1024];
                float hsv[CH];
                float pA = base[0], pB = base[64];
                #pragma unroll 4
                for (int tl = 0; tl < CH; ++tl) {
                    const float nA = base[(tl + 1) * XSTR];
                    const float nB = base[(tl + 1) * XSTR + 64];

                    const float ha0 = h;
                    const float ha1 = dpp_f<0x4E>(h);     // xor2  -> j^1
                    const float ha3 = dpp_f<0x141>(h);    // xor7  -> j^3
                    const float ha2 = dpp_f<0x4E>(ha3);   // xor5  -> j^2
                    const float ha7 = dpp_f<0x140>(h);    // xor15 -> j^7
                    const float ha4 = dpp_f<0x141>(ha7);  // xor8  -> j^4
                    const float ha5 = dpp_f<0x4E>(ha4);   // xor10 -> j^5
                    const float ha6 = dpp_f<0x1B>(ha7);   // xor12 -> j^6

                    float a0 = fmaf(wA[0], ha0, pA);
                    a0 = fmaf(wA[1], ha1, a0);
                    a0 = fmaf(wA[2], ha2, a0);
                    a0 = fmaf(wA[3], ha3, a0);
                    float a1 = wA[4] * ha4;
                    a1 = fmaf(wA[5], ha5, a1);
                    a1 = fmaf(wA[6], ha6, a1);
                    a1 = fmaf(wA[7], ha7, a1);
                    const float npA = a0 + a1;
                    float b0f = fmaf(wB[0], ha0, pB);
                    b0f = fmaf(wB[1], ha1, b0f);
                    b0f = fmaf(wB[2], ha2, b0f);
                    b0f = fmaf(wB[3], ha3, b0f);
                    float b1f = wB[4] * ha4;
                    b1f = fmaf(wB[5], ha5, b1f);
                    b1f = fmaf(wB[6], ha6, b1f);
                    b1f = fmaf(wB[7], ha7, b1f);
                    const float npB = b0f + b1f;

                    const float eA = rcp_f(1.f + exp2_f(npA));  // i or f
                    const float uB = rcp_f(1.f + exp2_f(npB));  // raw g or o
                    const float gg = fmaf(2.f, uB, -1.f);

                    const float myU = r ? eA : eA * gg;         // i*g or f
                    const float otU = dpp_f<0xB1>(myU);
                    const float fg  = r ? myU : otU;
                    const float igg = r ? otU : myU;
                    const float ogx = dpp_f<0xB1>(uB);
                    const float og  = r ? uB : ogx;

                    c = fmaf(fg, c, igg);
                    const float th =
                        fmaf(2.f, rcp_f(1.f + exp2_f(c * (-2.f * L2E))), -1.f);
                    h = og * th;
                    hsv[tl] = h;
                    pA = nA; pB = nB;
                }
                if (r == 0) {
                    #pragma unroll
                    for (int i = 0; i < CH; ++i)
                        hl[(i * 4 + s4) * 8 + j] = hsv[i];
                }
            }
        } else if (wid <= 2) {
            if (ck + 1 < NCK) {
                const int p = (wid - 1) * 64 + wl;
                produce_chunk(&xbuf[((ck + 1) & 1) * XBUF],
                              &cap[((ck + 1) & 1) * (4 * CSEQ)],
                              W_ih, b_ih, b_hh, featp, b0, ck + 1,
                              p & 31, p >> 5);
            }
        } else {
            if (ck >= 1)
                consume_chunk(&hlds[((ck - 1) & 1) * 1024], ostage,
                              W_out, b_out, out, b0, ck - 1, wl);
            if (ck + 2 < NCK)
                stage_chunk(cap, captions, b0, (ck + 2) & 1, ck + 2, wl, 64);
        }
        __syncthreads();
    }
}

// ---------------------------------------------------------------------------
// Workspace (floats): featp@0 (4*512*37 = 75,776) -- ~303 KB used
// ---------------------------------------------------------------------------
extern "C" void kernel_launch(void* const* d_in, const int* in_sizes, int n_in,
                              void* d_out, int out_size, void* d_ws, size_t ws_size,
                              hipStream_t stream) {
    const float* features = (const float*)d_in[0];
    const float* captions = (const float*)d_in[1];
    const float* W_in     = (const float*)d_in[2];
    const float* b_in     = (const float*)d_in[3];
    const float* W_ih     = (const float*)d_in[4];
    const float* W_hh     = (const float*)d_in[5];
    const float* b_ih     = (const float*)d_in[6];
    const float* b_hh     = (const float*)d_in[7];
    const float* W_out    = (const float*)d_in[8];
    const float* b_out    = (const float*)d_in[9];
    float* out = (float*)d_out;

    float* featp = (float*)d_ws;

    k_feat <<<dim3(BB, 4), 256, 0, stream>>>(features, W_in, b_in, featp);
    k_fused<<<128,         256, 0, stream>>>(captions, W_ih, b_ih, b_hh, W_hh,
                                             W_out, b_out, featp, out);
}

// Round 9
// 369.965 us; speedup vs baseline: 1.0324x; 1.0324x over previous
//
#include <hip/hip_runtime.h>
#include <math.h>

// Problem constants
#define BB   512   // batch
#define TT   256   // timesteps
#define CNNC 512   // channels
#define VV   37    // vocab
#define HH   8     // hidden
#define G4   32    // 4*H
#define CH   32    // chunk length (timesteps)
#define NCK  8     // TT/CH

#define L2E 1.4426950408889634f

// native 4-float vector for nontemporal builtins (HIP float4 is a class type)
typedef float f4_t __attribute__((ext_vector_type(4)));

// DPP cross-lane mov: pure VALU latency. quad_perm 0xB1=xor1, 0x4E=xor2,
// 0x1B=xor3; 0x141=row_half_mirror (xor7); 0x140=row_mirror (xor15).
template <int CTRL>
__device__ __forceinline__ float dpp_f(float x) {
    int r = __builtin_amdgcn_update_dpp(0, __float_as_int(x), CTRL, 0xF, 0xF, true);
    return __int_as_float(r);
}
__device__ __forceinline__ float rcp_f(float x) { return __builtin_amdgcn_rcpf(x); }
__device__ __forceinline__ float exp2_f(float x) { return __builtin_amdgcn_exp2f(x); }

// ---------------------------------------------------------------------------
// Kernel 1: avg-pool(features) @ W_in.T partial -> featp[quarter][B][V]
// (unchanged from R7)
// ---------------------------------------------------------------------------
__global__ __launch_bounds__(256) void k_feat(const float* __restrict__ features,
                                              const float* __restrict__ W_in,
                                              const float* __restrict__ b_in,
                                              float* __restrict__ featp) {
    __shared__ __align__(16) float raw[128 * 49];
    __shared__ float pooled[128];
    const int b = blockIdx.x, qt = blockIdx.y, tid = threadIdx.x;
    const f4_t* src =
        (const f4_t*)(features + (size_t)b * CNNC * 49 + qt * (128 * 49));
    f4_t* dst = (f4_t*)raw;
    for (int i = tid; i < 128 * 49 / 4; i += 256)
        dst[i] = __builtin_nontemporal_load(&src[i]);
    __syncthreads();
    if (tid < 128) {
        const float* p = raw + tid * 49;
        float s = 0.f;
        #pragma unroll
        for (int i = 0; i < 49; ++i) s += p[i];
        pooled[tid] = s;
    }
    __syncthreads();
    const int v = tid >> 2, pp = tid & 3;
    if (v < VV) {
        const float* w = W_in + v * CNNC + qt * 128 + pp * 32;
        const float* q = pooled + pp * 32;
        float s = 0.f;
        #pragma unroll
        for (int i = 0; i < 32; ++i) s += q[i] * w[i];
        s += __shfl_xor(s, 1);
        s += __shfl_xor(s, 2);
        if (pp == 0)
            featp[(qt * BB + b) * VV + v] =
                s * (1.f / 49.f) + (qt == 0 ? b_in[v] : 0.f);
    }
}

// ---------------------------------------------------------------------------
// Kernel 2: FUSED xproj + scan + softmax. 128 blocks x 4 waves, 1 block/CU.
//   wave 0: scan chunk ck (DPP LSTM) from xbuf[ck%2] -> hlds[ck%2]
//   waves 1,2: produce chunk ck+1 -> xbuf[(ck+1)%2].
//       R8 bug fixed: W_ih now lives in per-lane VGPRs (lane = gate), x is
//       broadcast from cap LDS via ds_read_b128 -- no global access at all.
//   wave 3: softmax chunk ck-1 (W_out/b_out in LDS) -> NT stores;
//       stage captions chunk ck+2 (+ feat row for chunk 0).
// ---------------------------------------------------------------------------
#define XSTR 133            // xbuf per-t stride
#define XBUF 4400           // floats per xbuf buffer
#define CSEQ 1280           // cap floats per seq (32 rows x 40)
#define OSTR 1188           // ostage per-seq stride

__device__ __forceinline__ void stage_chunk(float* __restrict__ cap,
                                            const float* __restrict__ captions,
                                            const float* __restrict__ featp,
                                            int b0, int buf, int cc,
                                            int lane, int nthreads) {
    float* cb = cap + buf * (4 * CSEQ);
    if (cc == 0) {
        // row 0 = feat (sum of the 4 channel-quarter partials)
        for (int i = lane; i < 4 * VV; i += nthreads) {
            const int s = i / VV, v = i - s * VV;
            const int b = b0 + s;
            cb[s * CSEQ + v] =
                featp[b * VV + v] + featp[(BB + b) * VV + v] +
                featp[(2 * BB + b) * VV + v] + featp[(3 * BB + b) * VV + v];
        }
        // rows 1..31 <- captions rows 0..30
        for (int i = lane; i < 4 * 1147; i += nthreads) {
            const int s = i / 1147, o = i - s * 1147;
            const int row = o / 37, v = o - row * 37;
            cb[s * CSEQ + (row + 1) * 40 + v] = __builtin_nontemporal_load(
                &captions[(size_t)(b0 + s) * TT * VV + o]);
        }
    } else {   // rows 0..31 <- captions rows cc*32-1 .. cc*32+30
        const int src0 = (cc * 32 - 1) * 37;
        for (int i = lane; i < 4 * 1184; i += nthreads) {
            const int s = i / 1184, o = i - s * 1184;
            const int row = o / 37, v = o - row * 37;
            cb[s * CSEQ + row * 40 + v] = __builtin_nontemporal_load(
                &captions[(size_t)(b0 + s) * TT * VV + src0 + o]);
        }
    }
}

// Producer: lane owns gate g (W row in VGPRs); x broadcast from cap LDS.
__device__ __forceinline__ void produce_chunk(float* __restrict__ xb,
                                              const float* __restrict__ cap_s,
                                              const float* __restrict__ wv,
                                              float bias,
                                              int wid, int wl) {
    const int g = wl & 31, half = wl >> 5;
    #pragma unroll 4
    for (int it = 0; it < 32; ++it) {
        const int rid = (wid - 1) * 64 + it * 2 + half;   // 0..127
        const int t = rid >> 2, s = rid & 3;
        const f4_t* xp = (const f4_t*)(cap_s + s * CSEQ + t * 40);
        float acc = bias;
        #pragma unroll
        for (int v4 = 0; v4 < 9; ++v4) {
            const f4_t x4 = xp[v4];
            acc = fmaf(wv[4 * v4 + 0], x4.x, acc);
            acc = fmaf(wv[4 * v4 + 1], x4.y, acc);
            acc = fmaf(wv[4 * v4 + 2], x4.z, acc);
            acc = fmaf(wv[4 * v4 + 3], x4.w, acc);
        }
        const f4_t x9 = xp[9];
        acc = fmaf(wv[36], x9.x, acc);
        xb[t * XSTR + g * 4 + s] = acc;
    }
}

__device__ __forceinline__ void consume_chunk(const float* __restrict__ hl,
                                              float* __restrict__ ostage,
                                              const float* __restrict__ Wo,
                                              const float* __restrict__ bo,
                                              float* __restrict__ out,
                                              int b0, int cc, int wl) {
    #pragma unroll
    for (int k = 0; k < 2; ++k) {
        const int rid = wl + 64 * k;
        const int s = rid >> 5, lt = rid & 31;
        const f4_t* hp = (const f4_t*)(hl + (lt * 4 + s) * 8);
        const f4_t h0 = hp[0], h1 = hp[1];
        const float hr[8] = {h0.x, h0.y, h0.z, h0.w, h1.x, h1.y, h1.z, h1.w};
        float z[VV], m = -1e30f;
        #pragma unroll
        for (int v = 0; v < VV; ++v) {
            const f4_t* wp = (const f4_t*)(Wo + v * 8);
            const f4_t w0 = wp[0], w1 = wp[1];
            float sv = bo[v];
            sv = fmaf(hr[0], w0.x, sv); sv = fmaf(hr[1], w0.y, sv);
            sv = fmaf(hr[2], w0.z, sv); sv = fmaf(hr[3], w0.w, sv);
            sv = fmaf(hr[4], w1.x, sv); sv = fmaf(hr[5], w1.y, sv);
            sv = fmaf(hr[6], w1.z, sv); sv = fmaf(hr[7], w1.w, sv);
            z[v] = sv; m = fmaxf(m, sv);
        }
        float sum = 0.f;
        #pragma unroll
        for (int v = 0; v < VV; ++v) { z[v] = exp2_f((z[v] - m) * L2E); sum += z[v]; }
        const float rs = rcp_f(sum);
        #pragma unroll
        for (int v = 0; v < VV; ++v) ostage[s * OSTR + lt * 37 + v] = z[v] * rs;
    }
    asm volatile("s_waitcnt lgkmcnt(0)" ::: "memory");
    for (int i = wl; i < 4 * 296; i += 64) {
        const int s = i / 296, o = i - s * 296;
        const f4_t val = *(const f4_t*)&ostage[s * OSTR + o * 4];
        f4_t* dst = (f4_t*)(out + ((size_t)(b0 + s) * TT + cc * 32) * VV) + o;
        __builtin_nontemporal_store(val, dst);
    }
}

__global__ __launch_bounds__(256) void k_fused(const float* __restrict__ captions,
                                               const float* __restrict__ W_ih,
                                               const float* __restrict__ b_ih,
                                               const float* __restrict__ b_hh,
                                               const float* __restrict__ W_hh,
                                               const float* __restrict__ W_out,
                                               const float* __restrict__ b_out,
                                               const float* __restrict__ featp,
                                               float* __restrict__ out) {
    __shared__ __align__(16) float cap[2 * 4 * CSEQ];   // 40960 B
    __shared__ __align__(16) float xbuf[2 * XBUF];      // 35200 B
    __shared__ __align__(16) float hlds[2 * 1024];      // 8192 B
    __shared__ __align__(16) float ostage[4 * OSTR];    // 19008 B
    __shared__ __align__(16) float Wo[VV * HH];         // 1184 B
    __shared__ float bo[VV];

    const int tid = threadIdx.x;
    const int wid = tid >> 6, wl = tid & 63;
    const int bg = blockIdx.x, b0 = bg * 4;

    // stage W_out/b_out once (all threads)
    for (int i = tid; i < VV * HH; i += 256) Wo[i] = W_out[i];
    if (tid < VV) bo[tid] = b_out[tid];

    // scanner per-lane setup (wave 0)
    float wA[HH] = {0}, wB[HH] = {0};
    int s4 = 0, j = 0, r = 0, roff = 0;
    // producer per-lane setup (waves 1,2): W row in VGPRs, pre-scaled
    float wv[37] = {0};
    float pbias = 0.f;
    if (wid == 0) {
        s4 = wl >> 4;
        const int q = wl & 15;
        j = q >> 1; r = q & 1;
        const int rowA = r * 8 + j, rowB = 16 + r * 8 + j;
        const float scA = -L2E, scB = r ? -L2E : (-2.f * L2E);
        #pragma unroll
        for (int m = 0; m < HH; ++m) {
            wA[m] = scA * W_hh[rowA * HH + (j ^ m)];
            wB[m] = scB * W_hh[rowB * HH + (j ^ m)];
        }
        roff = rowA * 4 + s4;
    } else if (wid <= 2) {
        const int g = wl & 31;
        const float sc = (g >= 16 && g < 24) ? (-2.f * L2E) : (-L2E);
        #pragma unroll
        for (int v = 0; v < VV; ++v) wv[v] = sc * W_ih[g * VV + v];
        pbias = sc * (b_ih[g] + b_hh[g]);
    }

    // prologue: stage cap chunks 0,1 (all threads), then produce chunk 0
    stage_chunk(cap, captions, featp, b0, 0, 0, tid, 256);
    stage_chunk(cap, captions, featp, b0, 1, 1, tid, 256);
    __syncthreads();
    if (wid == 1 || wid == 2)
        produce_chunk(&xbuf[0], &cap[0], wv, pbias, wid, wl);
    __syncthreads();

    float h = 0.f, c = 0.f;
    for (int ck = 0; ck <= NCK; ++ck) {
        if (wid == 0) {
            if (ck < NCK) {
                const float* base = &xbuf[(ck & 1) * XBUF] + roff;
                float* hl = &hlds[(ck & 1) * 1024];
                float hsv[CH];
                float pA = base[0], pB = base[64];
                #pragma unroll 4
                for (int tl = 0; tl < CH; ++tl) {
                    const float nA = base[(tl + 1) * XSTR];
                    const float nB = base[(tl + 1) * XSTR + 64];

                    const float ha0 = h;
                    const float ha1 = dpp_f<0x4E>(h);     // xor2  -> j^1
                    const float ha3 = dpp_f<0x141>(h);    // xor7  -> j^3
                    const float ha2 = dpp_f<0x4E>(ha3);   // xor5  -> j^2
                    const float ha7 = dpp_f<0x140>(h);    // xor15 -> j^7
                    const float ha4 = dpp_f<0x141>(ha7);  // xor8  -> j^4
                    const float ha5 = dpp_f<0x4E>(ha4);   // xor10 -> j^5
                    const float ha6 = dpp_f<0x1B>(ha7);   // xor12 -> j^6

                    float a0 = fmaf(wA[0], ha0, pA);
                    a0 = fmaf(wA[1], ha1, a0);
                    a0 = fmaf(wA[2], ha2, a0);
                    a0 = fmaf(wA[3], ha3, a0);
                    float a1 = wA[4] * ha4;
                    a1 = fmaf(wA[5], ha5, a1);
                    a1 = fmaf(wA[6], ha6, a1);
                    a1 = fmaf(wA[7], ha7, a1);
                    const float npA = a0 + a1;
                    float b0f = fmaf(wB[0], ha0, pB);
                    b0f = fmaf(wB[1], ha1, b0f);
                    b0f = fmaf(wB[2], ha2, b0f);
                    b0f = fmaf(wB[3], ha3, b0f);
                    float b1f = wB[4] * ha4;
                    b1f = fmaf(wB[5], ha5, b1f);
                    b1f = fmaf(wB[6], ha6, b1f);
                    b1f = fmaf(wB[7], ha7, b1f);
                    const float npB = b0f + b1f;

                    const float eA = rcp_f(1.f + exp2_f(npA));  // i or f
                    const float uB = rcp_f(1.f + exp2_f(npB));  // raw g or o
                    const float gg = fmaf(2.f, uB, -1.f);

                    const float myU = r ? eA : eA * gg;         // i*g or f
                    const float otU = dpp_f<0xB1>(myU);
                    const float fg  = r ? myU : otU;
                    const float igg = r ? otU : myU;
                    const float ogx = dpp_f<0xB1>(uB);
                    const float og  = r ? uB : ogx;

                    c = fmaf(fg, c, igg);
                    const float th =
                        fmaf(2.f, rcp_f(1.f + exp2_f(c * (-2.f * L2E))), -1.f);
                    h = og * th;
                    hsv[tl] = h;
                    pA = nA; pB = nB;
                }
                if (r == 0) {
                    #pragma unroll
                    for (int i = 0; i < CH; ++i)
                        hl[(i * 4 + s4) * 8 + j] = hsv[i];
                }
            }
        } else if (wid <= 2) {
            if (ck + 1 < NCK)
                produce_chunk(&xbuf[((ck + 1) & 1) * XBUF],
                              &cap[((ck + 1) & 1) * (4 * CSEQ)],
                              wv, pbias, wid, wl);
        } else {
            if (ck >= 1)
                consume_chunk(&hlds[((ck - 1) & 1) * 1024], ostage,
                              Wo, bo, out, b0, ck - 1, wl);
            if (ck + 2 < NCK)
                stage_chunk(cap, captions, featp, b0, (ck + 2) & 1, ck + 2,
                            wl, 64);
        }
        __syncthreads();
    }
}

// ---------------------------------------------------------------------------
// Workspace (floats): featp@0 (4*512*37 = 75,776) -- ~303 KB used
// ---------------------------------------------------------------------------
extern "C" void kernel_launch(void* const* d_in, const int* in_sizes, int n_in,
                              void* d_out, int out_size, void* d_ws, size_t ws_size,
                              hipStream_t stream) {
    const float* features = (const float*)d_in[0];
    const float* captions = (const float*)d_in[1];
    const float* W_in     = (const float*)d_in[2];
    const float* b_in     = (const float*)d_in[3];
    const float* W_ih     = (const float*)d_in[4];
    const float* W_hh     = (const float*)d_in[5];
    const float* b_ih     = (const float*)d_in[6];
    const float* b_hh     = (const float*)d_in[7];
    const float* W_out    = (const float*)d_in[8];
    const float* b_out    = (const float*)d_in[9];
    float* out = (float*)d_out;

    float* featp = (float*)d_ws;

    k_feat <<<dim3(BB, 4), 256, 0, stream>>>(features, W_in, b_in, featp);
    k_fused<<<128,         256, 0, stream>>>(captions, W_ih, b_ih, b_hh, W_hh,
                                             W_out, b_out, featp, out);
}